// Round 12
// baseline (1612.560 us; speedup 1.0000x reference)
//
#include <hip/hip_runtime.h>
#include <math.h>

#define PI_F 3.14159265358979323846f

typedef _Float16 half8 __attribute__((ext_vector_type(8)));
typedef _Float16 half4 __attribute__((ext_vector_type(4)));
typedef float f32x4 __attribute__((ext_vector_type(4)));

#define MFMA(a, b, c) __builtin_amdgcn_mfma_f32_16x16x32_f16(a, b, c, 0, 0, 0)
#define OFF_CAT 49152   // halfs: wcat starts after whh0 (3*128*128)

__device__ __forceinline__ float rcp_fast(float x) { return __builtin_amdgcn_rcpf(x); }
__device__ __forceinline__ float sigmoid_f(float x) {
    float e = __expf(-x);
    return rcp_fast(1.0f + e);
}
__device__ __forceinline__ float tanh_f(float x) {
    float ax = fabsf(x);
    float e  = __expf(-2.0f * ax);
    float t  = (1.0f - e) * rcp_fast(1.0f + e);
    return x >= 0.0f ? t : -t;
}

// Prep: f16 weights; concat [w_ih1|w_hh1] along K for layer 1.
__global__ void prep_kernel(const float* __restrict__ whh0,
                            const float* __restrict__ wih1,
                            const float* __restrict__ whh1,
                            _Float16* __restrict__ wsp) {
    int i = blockIdx.x * 256 + threadIdx.x;
    if (i < 49152) wsp[i] = (_Float16)whh0[i];
    if (i < 98304) {
        int n = i >> 8, k = i & 255;
        float v = (k < 128) ? wih1[(n << 7) + k] : whh1[(n << 7) + k - 128];
        wsp[OFF_CAT + i] = (_Float16)v;
    }
}

// 512 threads (8 waves), 64 elems/block, 1 block/CU, 2 waves/SIMD, 256 regs.
// r11 base (1539us): 16 dims/wave both layers, weights resident (144 regs,
// "+v"-pinned), own-dim h state in f32 registers, f16 h planes in LDS.
//
// Round-12 change: TWO ELEMENT GROUPS, HALF-TICK OFFSET. Elements are fully
// independent; E0 = block elems 0-31, E1 = 32-63 share the same weight regs.
// Iteration k:
//   Half 1: A(E0,k) || B(E1,k-1) || head(E0,k-1)   | bar
//   Half 2: B(E0,k) || A(E1,k)   || head(E1,k-1)   | bar
// Every window now mixes an A-chain + B-chain + epilogues on INDEPENDENT data
// within the SAME wave -> epilogue VALU overlaps MFMA via pure ILP (the
// cross-wave overlap levers are all falsified; this needs no wave drift).
// Barrier count, MFMA count, LDS traffic, per-element arithmetic: identical
// to r11 -> absmax must reproduce bit-exactly.
//
// Parity audit (cur=k&1, prv=cur^1):
//  H1: A(E0,k) rd h0g[0][prv], wr h0g[0][cur]; B(E1,k-1) rd h0g[1][prv] +
//      h1g[1][cur], wr h1g[1][prv]; head(E0,k-1) rd h1g[0][prv].
//      Writes {h0g0[cur], h1g1[prv]} vs reads -> disjoint slices/parities.
//  H2: B(E0,k) rd h0g[0][cur](H1,post-bar) + h1g[0][prv], wr h1g[0][cur];
//      A(E1,k) rd h0g[1][prv], wr h0g[1][cur]; head(E1,k-1) rd h1g[1][prv]
//      (written H1, post-bar). Writes {h1g0[cur], h0g1[cur]} -> disjoint.
//  Cross-iter WAR/RAW all separated by >=1 barrier (checked per array).
//
// Per-group h planes (32 elems) in MFMA-B-frag chunk order:
//   plane[(kc*2+eb)*512 + (qd*16+l4)*8 + j] = h[e=eb*16+l4][dim=32kc+8qd+j]

__global__ void __launch_bounds__(512, 2) rnn_wf_pipe(
    const int*   __restrict__ x,
    const float* __restrict__ w_ih0,
    const float* __restrict__ w_lin,
    const float* __restrict__ b_lin,
    const _Float16* __restrict__ wsp,
    float*       __restrict__ out,
    int nbatch)
{
    __shared__ _Float16 h0g[2][2][4096];       // [group][buf][plane]
    __shared__ _Float16 h1g[2][2][4096];
    __shared__ float gi0T[2][3][128];          // [prev-bit][gate][dim]
    __shared__ float wlinT[256];               // w_lin flat
    __shared__ unsigned long long bmk[64];     // per-element bit mask

    const int t    = threadIdx.x;
    const int wv   = t >> 6;                   // 0..7 = dim-block (16 dims)
    const int l4   = t & 15;
    const int q    = (t >> 4) & 3;
    const int ebg  = blockIdx.x * 64;

    // ---- init LDS ----
    for (int i = t; i < 8192; i += 512) {      // 8192 ints = 2 grp x 2 buf x 4096 halfs
        ((int*)h0g)[i] = 0; ((int*)h1g)[i] = 0;
    }
    for (int i = t; i < 768; i += 512) {
        int b = i / 384, rem = i - b * 384;
        ((float*)gi0T)[b * 384 + rem] = w_ih0[rem * 2 + b];
    }
    if (t < 256) wlinT[t] = w_lin[t];
    if (t < 256) {   // bit masks: thread t -> element t>>2, quarter t&3
        int el = t >> 2, qq = t & 3;
        int eg = ebg + el; if (eg >= nbatch) eg = nbatch - 1;
        const int* xr = x + (size_t)eg * 64 + qq * 16;
        unsigned long long m = 0ull;
#pragma unroll
        for (int i = 0; i < 16; ++i)
            m |= ((unsigned long long)((unsigned)(xr[i] + 1) >> 1)) << (qq * 16 + i);
        m |= __shfl_xor(m, 1);
        m |= __shfl_xor(m, 2);
        if (qq == 0) bmk[el] = m;
    }

    const int lo8 = ((q << 4) + l4) << 3;      // = lane*8 halfs: B-frag chunk offset
    const int d0  = wv * 16 + 4 * q;           // first of 4 dims this lane updates
    const int epc = (d0 >> 5) * 1024 + ((d0 >> 3) & 3) * 128 + l4 * 8 + (d0 & 7);

    // ---- register-resident weights ----
    half8 w0[3][4];                            // 48 regs
#pragma unroll
    for (int g = 0; g < 3; ++g)
#pragma unroll
        for (int kc = 0; kc < 4; ++kc)
            w0[g][kc] = *(const half8*)(wsp + (size_t)(g * 128 + 16 * wv + l4) * 128 + 32 * kc + 8 * q);
    half8 w1[3][8];                            // 96 regs
#pragma unroll
    for (int g = 0; g < 3; ++g)
#pragma unroll
        for (int kc = 0; kc < 8; ++kc)
            w1[g][kc] = *(const half8*)(wsp + OFF_CAT + (size_t)(g * 128 + 16 * wv + l4) * 256 + 32 * kc + 8 * q);

    // ---- own-dim h state in f32 registers (per group, statically indexed) ----
    f32x4 hs0E0[2], hs1E0[2], hs0E1[2], hs1E1[2];
#pragma unroll
    for (int eb = 0; eb < 2; ++eb) {
        hs0E0[eb] = (f32x4){0.f,0.f,0.f,0.f};
        hs1E0[eb] = (f32x4){0.f,0.f,0.f,0.f};
        hs0E1[eb] = (f32x4){0.f,0.f,0.f,0.f};
        hs1E1[eb] = (f32x4){0.f,0.f,0.f,0.f};
    }

    // head state: waves 0-1 -> E0, waves 2-3 -> E1; q-replicated
    float amp = 1.0f, phs = 0.0f, nu = 0.0f, nd = 0.0f;
    float bl0 = 0.0f, bl1 = 0.0f;
    const int wvh  = wv & 1;
    const int ehl  = (wvh << 4) + l4;          // elem within group
    const int bmki = (((wv >> 1) & 1) << 5) + ehl;
    if (wv < 4) { bl0 = b_lin[0]; bl1 = b_lin[1]; }

    __syncthreads();

#define PHASE_A(HR, HW, ST, GOFF, TICK)                                      \
    {                                                                        \
        _Pragma("unroll")                                                    \
        for (int eb = 0; eb < 2; ++eb) {                                     \
            f32x4 aR = {0,0,0,0}, aZ = {0,0,0,0}, aN = {0,0,0,0};            \
            _Pragma("unroll")                                                \
            for (int kc = 0; kc < 4; ++kc) {                                 \
                const int cb = (kc * 2 + eb) * 512 + lo8;                    \
                half8 hh = *(const half8*)&(HR)[cb];                         \
                aR = MFMA(w0[0][kc], hh, aR);                                \
                aZ = MFMA(w0[1][kc], hh, aZ);                                \
                aN = MFMA(w0[2][kc], hh, aN);                                \
            }                                                                \
            f32x4 giR = {0,0,0,0}, giZ = {0,0,0,0}, giN = {0,0,0,0};         \
            if ((TICK) > 0) {                                                \
                const int e = (GOFF) + eb * 16 + l4;                         \
                int pb = (int)((bmk[e] >> ((TICK) - 1)) & 1ull);             \
                const float* gp = &gi0T[pb][0][0];                           \
                giR = *(const f32x4*)(gp + d0);                              \
                giZ = *(const f32x4*)(gp + 128 + d0);                        \
                giN = *(const f32x4*)(gp + 256 + d0);                        \
            }                                                                \
            const int ep_ = epc + eb * 512;                                  \
            f32x4 hp = (ST)[eb];                                             \
            f32x4 hnv; half4 nh;                                             \
            _Pragma("unroll")                                                \
            for (int r = 0; r < 4; ++r) {                                    \
                float rr = sigmoid_f(giR[r] + aR[r]);                        \
                float zz = sigmoid_f(giZ[r] + aZ[r]);                        \
                float nn = tanh_f(giN[r] + rr * aN[r]);                      \
                float hn = (1.0f - zz) * nn + zz * hp[r];                    \
                hnv[r] = hn; nh[r] = (_Float16)hn;                           \
            }                                                                \
            (ST)[eb] = hnv;                                                  \
            *(half4*)&(HW)[ep_] = nh;                                        \
        }                                                                    \
    }

#define PHASE_B(H0R, H1R, H1W, ST)                                          \
    {                                                                        \
        _Pragma("unroll")                                                    \
        for (int eb = 0; eb < 2; ++eb) {                                     \
            f32x4 aR = {0,0,0,0}, aZ = {0,0,0,0};                            \
            f32x4 aNi = {0,0,0,0}, aNh = {0,0,0,0};                          \
            _Pragma("unroll")                                                \
            for (int kc = 0; kc < 8; ++kc) {                                 \
                const int cb = ((kc & 3) * 2 + eb) * 512 + lo8;              \
                half8 hh;                                                    \
                if (kc < 4) hh = *(const half8*)&(H0R)[cb];                  \
                else        hh = *(const half8*)&(H1R)[cb];                  \
                aR = MFMA(w1[0][kc], hh, aR);                                \
                aZ = MFMA(w1[1][kc], hh, aZ);                                \
                if (kc < 4) aNi = MFMA(w1[2][kc], hh, aNi);                  \
                else        aNh = MFMA(w1[2][kc], hh, aNh);                  \
            }                                                                \
            const int ep_ = epc + eb * 512;                                  \
            f32x4 hp = (ST)[eb];                                             \
            f32x4 hnv; half4 nh;                                             \
            _Pragma("unroll")                                                \
            for (int r = 0; r < 4; ++r) {                                    \
                float rr = sigmoid_f(aR[r]);                                 \
                float zz = sigmoid_f(aZ[r]);                                 \
                float nn = tanh_f(aNi[r] + rr * aNh[r]);                     \
                float hn = (1.0f - zz) * nn + zz * hp[r];                    \
                hnv[r] = hn; nh[r] = (_Float16)hn;                           \
            }                                                                \
            (ST)[eb] = hnv;                                                  \
            *(half4*)&(H1W)[ep_] = nh;                                       \
        }                                                                    \
    }

#define HEAD(H1B, S)                                                         \
    {                                                                        \
        float l0 = 0.0f, l1 = 0.0f;                                          \
        _Pragma("unroll")                                                    \
        for (int ks = 0; ks < 4; ++ks) {                                     \
            const int cb = (ks * 2 + wvh) * 512 + lo8;                       \
            half8 hh = *(const half8*)&(H1B)[cb];                            \
            const float* wpl = &wlinT[32 * ks + 8 * q];                      \
            _Pragma("unroll")                                                \
            for (int j = 0; j < 8; ++j) {                                    \
                float hv = (float)hh[j];                                     \
                l0 = fmaf(hv, wpl[j], l0);                                   \
                l1 = fmaf(hv, wpl[128 + j], l1);                             \
            }                                                                \
        }                                                                    \
        l0 += __shfl_xor(l0, 16); l0 += __shfl_xor(l0, 32); l0 += bl0;       \
        l1 += __shfl_xor(l1, 16); l1 += __shfl_xor(l1, 32); l1 += bl1;       \
        float p0 = sigmoid_f(l0 - l1);                                       \
        float p1 = sigmoid_f(l1 - l0);                                       \
        float y0 = sqrtf(p0), y1 = sqrtf(p1);                                \
        float ph0 = PI_F * l0 * rcp_fast(1.0f + fabsf(l0));                  \
        float ph1 = PI_F * l1 * rcp_fast(1.0f + fabsf(l1));                  \
        int bit = (int)((bmk[bmki] >> (S)) & 1ull);                          \
        bool is_even = ((S) & 1) == 0;                                       \
        float num   = is_even ? nu : nd;                                     \
        float lower = -16.0f + (float)((S) >> 1);                            \
        float occ   = (num < 16.0f) ? 1.0f : 0.0f;                           \
        float unocc = (num > lower) ? 1.0f : 0.0f;                           \
        if ((S) >= 16) {                                                     \
            float m0 = y0 * unocc, m1 = y1 * occ;                            \
            float nrm = fmaxf(sqrtf(m0 * m0 + m1 * m1), 1e-12f);             \
            float rn  = rcp_fast(nrm);                                       \
            y0 = m0 * rn; y1 = m1 * rn;                                      \
        }                                                                    \
        if (is_even) nu += (float)bit; else nd += (float)bit;                \
        amp *= bit ? y1 : y0;                                                \
        phs += bit ? ph1 : ph0;                                              \
    }

    for (int k = 0; k <= 64; ++k) {
        const int cur = k & 1, prv = cur ^ 1;

        // pin weights: opaque loop-carried registers (no remat from memory)
#pragma unroll
        for (int g = 0; g < 3; ++g) {
#pragma unroll
            for (int kc = 0; kc < 4; ++kc) asm volatile("" : "+v"(w0[g][kc]));
#pragma unroll
            for (int kc = 0; kc < 8; ++kc) asm volatile("" : "+v"(w1[g][kc]));
        }

        // ---- half 1: A(E0,k) || B(E1,k-1) || head(E0,k-1) ----
        if (k < 64) PHASE_A(h0g[0][prv], h0g[0][cur], hs0E0, 0, k);
        if (k >= 1) PHASE_B(h0g[1][prv], h1g[1][cur], h1g[1][prv], hs1E1);
        if (k >= 1 && wv < 2) HEAD(h1g[0][prv], k - 1);

        __syncthreads();

        // ---- half 2: B(E0,k) || A(E1,k) || head(E1,k-1) ----
        if (k < 64) PHASE_B(h0g[0][cur], h1g[0][prv], h1g[0][cur], hs1E0);
        if (k < 64) PHASE_A(h0g[1][prv], h0g[1][cur], hs0E1, 32, k);
        if (k >= 1 && wv >= 2 && wv < 4) HEAD(h1g[1][prv], k - 1);

        __syncthreads();
    }

    if (wv < 4 && q == 0) {
        int eg = ebg + (((wv >> 1) & 1) << 5) + ehl;
        if (eg < nbatch) {
            float s, c;
            sincosf(phs, &s, &c);
            out[eg]          = amp * c;
            out[nbatch + eg] = amp * s;
        }
    }
}

extern "C" void kernel_launch(void* const* d_in, const int* in_sizes, int n_in,
                              void* d_out, int out_size, void* d_ws, size_t ws_size,
                              hipStream_t stream) {
    const int*   x     = (const int*)  d_in[0];
    const float* w_ih0 = (const float*)d_in[1];
    const float* w_hh0 = (const float*)d_in[2];
    const float* w_ih1 = (const float*)d_in[3];
    const float* w_hh1 = (const float*)d_in[4];
    const float* w_lin = (const float*)d_in[5];
    const float* b_lin = (const float*)d_in[6];
    float* out = (float*)d_out;
    _Float16* wsp = (_Float16*)d_ws;

    const int nbatch = in_sizes[0] / 64;

    prep_kernel<<<384, 256, 0, stream>>>(w_hh0, w_ih1, w_hh1, wsp);

    const int blocks = (nbatch + 63) / 64;
    rnn_wf_pipe<<<blocks, 512, 0, stream>>>(x, w_ih0, w_lin, b_lin, wsp, out, nbatch);
}

// Round 13
// 1587.172 us; speedup vs baseline: 1.0160x; 1.0160x over previous
//
#include <hip/hip_runtime.h>
#include <math.h>

#define PI_F 3.14159265358979323846f

typedef _Float16 half8 __attribute__((ext_vector_type(8)));
typedef _Float16 half4 __attribute__((ext_vector_type(4)));
typedef float f32x4 __attribute__((ext_vector_type(4)));

#define MFMA(a, b, c) __builtin_amdgcn_mfma_f32_16x16x32_f16(a, b, c, 0, 0, 0)
#define OFF_CAT 49152   // halfs: wcat starts after whh0 (3*128*128)

__device__ __forceinline__ float rcp_fast(float x) { return __builtin_amdgcn_rcpf(x); }
__device__ __forceinline__ float sigmoid_f(float x) {
    float e = __expf(-x);
    return rcp_fast(1.0f + e);
}
__device__ __forceinline__ float tanh_f(float x) {
    float ax = fabsf(x);
    float e  = __expf(-2.0f * ax);
    float t  = (1.0f - e) * rcp_fast(1.0f + e);
    return x >= 0.0f ? t : -t;
}

// Prep: f16 weights; concat [w_ih1|w_hh1] along K for layer 1.
__global__ void prep_kernel(const float* __restrict__ whh0,
                            const float* __restrict__ wih1,
                            const float* __restrict__ whh1,
                            _Float16* __restrict__ wsp) {
    int i = blockIdx.x * 256 + threadIdx.x;
    if (i < 49152) wsp[i] = (_Float16)whh0[i];
    if (i < 98304) {
        int n = i >> 8, k = i & 255;
        float v = (k < 128) ? wih1[(n << 7) + k] : whh1[(n << 7) + k - 128];
        wsp[OFF_CAT + i] = (_Float16)v;
    }
}

// 512 threads (8 waves), 64 elems/block, 1 block/CU, 2 waves/SIMD, 256 regs.
// r11 base (1539us, best): 16 dims/wave both layers, weights resident (144
// regs, "+v"-pinned), own-dim h state in f32 registers, f16 h planes in LDS,
// 2 barriers/tick { A | bar | B | bar | head || A(t+1) }.
// Falsified levers (do not revisit): barrier fusion (r3/r7/r9), layer-split
// waves (r6), AGPR weight pins (r10), half-tick element interleave (r12).
//
// Round-13 change: CROSS-BARRIER OPERAND PREFETCH. The compiler cannot hoist
// ds_reads across __syncthreads, so each barrier exit pays an exposed
// lgkmcnt wait before the first MFMA. Both hoists are legal by parity:
//  - pfA (eb0/eb1, kc0-3 of h0[prv-next]): issued in the B window. A(t+1)
//    reads h0[cur(t)], written by A(t) before bar1(t) -> stable through B.
//  - pfB (eb0/eb1, k-chunks 0-3 of h1[prv]): issued before bar1. B(t) reads
//    h1[prv] written by B(t-1) before bar2(t-1) -> stable through A(t).
// B's kc loop is reordered h1-FIRST (kc4-7 then kc0-3): the prefetched h1
// MFMAs execute while the just-written h0[cur] reads are in flight. This
// changes aR/aZ accumulation order (h1 terms first) -> absmax shifts ~1e-9.
//
// h planes (64 elems) in MFMA-B-frag chunk order, double-buffered by parity:
//   plane[buf][(kc*4 + eb)*512 + (qd*16 + l4)*8 + j] = h[e=eb*16+l4][dim=32kc+8qd+j]

__global__ void __launch_bounds__(512, 2) rnn_wf_pipe(
    const int*   __restrict__ x,
    const float* __restrict__ w_ih0,
    const float* __restrict__ w_lin,
    const float* __restrict__ b_lin,
    const _Float16* __restrict__ wsp,
    float*       __restrict__ out,
    int nbatch)
{
    __shared__ _Float16 h0[2][8192], h1[2][8192];
    __shared__ float gi0T[2][3][128];          // [prev-bit][gate][dim]
    __shared__ float wlinT[256];               // w_lin flat
    __shared__ unsigned long long bmk[64];     // per-element bit mask

    const int t    = threadIdx.x;
    const int wv   = t >> 6;                   // 0..7 = dim-block (16 dims)
    const int l4   = t & 15;
    const int q    = (t >> 4) & 3;
    const int ebg  = blockIdx.x * 64;

    // ---- init LDS ----
    for (int i = t; i < 8192; i += 512) {      // 8192 ints = 2 bufs x 8192 halfs per array
        ((int*)h0)[i] = 0; ((int*)h1)[i] = 0;
    }
    for (int i = t; i < 768; i += 512) {
        int b = i / 384, rem = i - b * 384;
        ((float*)gi0T)[b * 384 + rem] = w_ih0[rem * 2 + b];
    }
    if (t < 256) wlinT[t] = w_lin[t];
    if (t < 256) {   // bit masks: thread t -> element t>>2, quarter t&3
        int el = t >> 2, qq = t & 3;
        int eg = ebg + el; if (eg >= nbatch) eg = nbatch - 1;
        const int* xr = x + (size_t)eg * 64 + qq * 16;
        unsigned long long m = 0ull;
#pragma unroll
        for (int i = 0; i < 16; ++i)
            m |= ((unsigned long long)((unsigned)(xr[i] + 1) >> 1)) << (qq * 16 + i);
        m |= __shfl_xor(m, 1);
        m |= __shfl_xor(m, 2);
        if (qq == 0) bmk[el] = m;
    }

    const int lo8 = ((q << 4) + l4) << 3;      // = lane*8 halfs: B-frag chunk offset
    const int d0  = wv * 16 + 4 * q;           // first of 4 dims this lane updates
    const int epb = (d0 >> 5) * 2048 + ((d0 >> 3) & 3) * 128 + l4 * 8 + (d0 & 7);

    // ---- register-resident weights ----
    half8 w0[3][4];                            // 48 regs
#pragma unroll
    for (int g = 0; g < 3; ++g)
#pragma unroll
        for (int kc = 0; kc < 4; ++kc)
            w0[g][kc] = *(const half8*)(wsp + (size_t)(g * 128 + 16 * wv + l4) * 128 + 32 * kc + 8 * q);
    half8 w1[3][8];                            // 96 regs
#pragma unroll
    for (int g = 0; g < 3; ++g)
#pragma unroll
        for (int kc = 0; kc < 8; ++kc)
            w1[g][kc] = *(const half8*)(wsp + OFF_CAT + (size_t)(g * 128 + 16 * wv + l4) * 256 + 32 * kc + 8 * q);

    // ---- own-dim h state in f32 registers (statically indexed) ----
    f32x4 h0s[4], h1s[4];
#pragma unroll
    for (int eb = 0; eb < 4; ++eb) {
        h0s[eb] = (f32x4){0.f, 0.f, 0.f, 0.f};
        h1s[eb] = (f32x4){0.f, 0.f, 0.f, 0.f};
    }

    // head state (waves 0-3, q-replicated)
    float amp = 1.0f, phs = 0.0f, nu = 0.0f, nd = 0.0f;
    float bl0 = 0.0f, bl1 = 0.0f;
    const int eh = (wv << 4) + l4;
    if (wv < 4) { bl0 = b_lin[0]; bl1 = b_lin[1]; }

    __syncthreads();

    // ---- cross-barrier prefetch registers (eb0/eb1 only) ----
    half8 pfA[2][4];   // A's h0[prv] frags, kc0-3
    half8 pfB[2][4];   // B's h1[prv] frags, k-chunks 0-3 (= kc4-7 operands)

    // prime pfA for tick 0 (reads zero-init h0[1])
#pragma unroll
    for (int eb = 0; eb < 2; ++eb)
#pragma unroll
        for (int kc = 0; kc < 4; ++kc)
            pfA[eb][kc] = *(const half8*)&h0[1][(kc * 4 + eb) * 512 + lo8];

    for (int tick = 0; tick < 64; ++tick) {
        const int cur = tick & 1, prv = cur ^ 1;

        // pin weights: opaque loop-carried registers (no remat from memory)
#pragma unroll
        for (int g = 0; g < 3; ++g) {
#pragma unroll
            for (int kc = 0; kc < 4; ++kc) asm volatile("" : "+v"(w0[g][kc]));
#pragma unroll
            for (int kc = 0; kc < 8; ++kc) asm volatile("" : "+v"(w1[g][kc]));
        }

        // ---- Phase A: h0(tick) = GRU0(onehot(bit(tick-1)), h0(tick-1)) ----
        //      eb0/eb1 operands come from pfA (prefetched during last B window)
#pragma unroll
        for (int eb = 0; eb < 4; ++eb) {
            f32x4 aR = {0,0,0,0}, aZ = {0,0,0,0}, aN = {0,0,0,0};
#pragma unroll
            for (int kc = 0; kc < 4; ++kc) {
                const int cb = (kc * 4 + eb) * 512 + lo8;
                half8 hh = (eb < 2) ? pfA[eb & 1][kc]
                                    : *(const half8*)&h0[prv][cb];
                aR = MFMA(w0[0][kc], hh, aR);
                aZ = MFMA(w0[1][kc], hh, aZ);
                aN = MFMA(w0[2][kc], hh, aN);
            }
            const int e = eb * 16 + l4;
            f32x4 giR = {0,0,0,0}, giZ = {0,0,0,0}, giN = {0,0,0,0};
            if (tick > 0) {
                int pb = (int)((bmk[e] >> (tick - 1)) & 1ull);
                const float* gp = &gi0T[pb][0][0];
                giR = *(const f32x4*)(gp + d0);
                giZ = *(const f32x4*)(gp + 128 + d0);
                giN = *(const f32x4*)(gp + 256 + d0);
            }
            const int ep_ = epb + eb * 512;
            f32x4 hp = h0s[eb];
            f32x4 hnv;
            half4 nh;
#pragma unroll
            for (int r = 0; r < 4; ++r) {
                float rr = sigmoid_f(giR[r] + aR[r]);
                float zz = sigmoid_f(giZ[r] + aZ[r]);
                float nn = tanh_f(giN[r] + rr * aN[r]);
                float hn = (1.0f - zz) * nn + zz * hp[r];
                hnv[r] = hn;
                nh[r] = (_Float16)hn;
            }
            h0s[eb] = hnv;
            *(half4*)&h0[cur][ep_] = nh;
        }

        // prefetch pfB before bar1: h1[prv] (written by B(tick-1) pre-bar2,
        // stable through this A window) -> arrives during barrier drain
#pragma unroll
        for (int eb = 0; eb < 2; ++eb)
#pragma unroll
            for (int kk = 0; kk < 4; ++kk)
                pfB[eb][kk] = *(const half8*)&h1[prv][(kk * 4 + eb) * 512 + lo8];

        __syncthreads();

        // ---- Phase B: h1(tick) = GRU1(h0(tick), h1(tick-1)) ----
        //      h1 terms FIRST (kc4-7, prefetched for eb0/eb1): these MFMAs
        //      run while the just-written h0[cur] reads are in flight.
#pragma unroll
        for (int eb = 0; eb < 4; ++eb) {
            f32x4 aR = {0,0,0,0}, aZ = {0,0,0,0};
            f32x4 aNi = {0,0,0,0}, aNh = {0,0,0,0};
#pragma unroll
            for (int kk = 0; kk < 4; ++kk) {   // kc = kk+4 : h1[prv] operand
                const int cb = (kk * 4 + eb) * 512 + lo8;
                half8 hh = (eb < 2) ? pfB[eb & 1][kk]
                                    : *(const half8*)&h1[prv][cb];
                aR  = MFMA(w1[0][kk + 4], hh, aR);
                aZ  = MFMA(w1[1][kk + 4], hh, aZ);
                aNh = MFMA(w1[2][kk + 4], hh, aNh);
            }
#pragma unroll
            for (int kc = 0; kc < 4; ++kc) {   // h0[cur] operand
                const int cb = (kc * 4 + eb) * 512 + lo8;
                half8 hh = *(const half8*)&h0[cur][cb];
                aR  = MFMA(w1[0][kc], hh, aR);
                aZ  = MFMA(w1[1][kc], hh, aZ);
                aNi = MFMA(w1[2][kc], hh, aNi);
            }
            const int ep_ = epb + eb * 512;
            f32x4 hp = h1s[eb];
            f32x4 hnv;
            half4 nh;
#pragma unroll
            for (int r = 0; r < 4; ++r) {
                float rr = sigmoid_f(aR[r]);
                float zz = sigmoid_f(aZ[r]);
                float nn = tanh_f(aNi[r] + rr * aNh[r]);
                float hn = (1.0f - zz) * nn + zz * hp[r];
                hnv[r] = hn;
                nh[r] = (_Float16)hn;
            }
            h1s[eb] = hnv;
            *(half4*)&h1[cur][ep_] = nh;
        }

        // prefetch pfA for A(tick+1) before bar2: reads h0[cur], written by
        // A(tick) pre-bar1, stable until A(tick+2) -> legal hoist
#pragma unroll
        for (int eb = 0; eb < 2; ++eb)
#pragma unroll
            for (int kc = 0; kc < 4; ++kc)
                pfA[eb][kc] = *(const half8*)&h0[cur][(kc * 4 + eb) * 512 + lo8];

        __syncthreads();

        // ---- head for step s = tick; h1(s) in buf cur.  Waves 0-3 only;
        //      waves 4-7 proceed straight into A(tick+1) (disjoint arrays).
        //      Lane-linear reads (conflict-free); xor-16/32 reduce. ----
        if (wv < 4) {
            const int s = tick;
            float l0 = 0.0f, l1 = 0.0f;
#pragma unroll
            for (int ks = 0; ks < 4; ++ks) {
                const int cb = (ks * 4 + wv) * 512 + lo8;
                half8 hh = *(const half8*)&h1[cur][cb];
                const float* wpl = &wlinT[32 * ks + 8 * q];
#pragma unroll
                for (int j = 0; j < 8; ++j) {
                    float hv = (float)hh[j];
                    l0 = fmaf(hv, wpl[j], l0);
                    l1 = fmaf(hv, wpl[128 + j], l1);
                }
            }
            l0 += __shfl_xor(l0, 16); l0 += __shfl_xor(l0, 32); l0 += bl0;
            l1 += __shfl_xor(l1, 16); l1 += __shfl_xor(l1, 32); l1 += bl1;

            float p0 = sigmoid_f(l0 - l1);
            float p1 = sigmoid_f(l1 - l0);
            float y0 = sqrtf(p0), y1 = sqrtf(p1);
            float ph0 = PI_F * l0 * rcp_fast(1.0f + fabsf(l0));
            float ph1 = PI_F * l1 * rcp_fast(1.0f + fabsf(l1));

            int bit = (int)((bmk[eh] >> s) & 1ull);
            bool is_even = (s & 1) == 0;
            float num   = is_even ? nu : nd;
            float lower = -16.0f + (float)(s >> 1);
            float occ   = (num < 16.0f) ? 1.0f : 0.0f;
            float unocc = (num > lower) ? 1.0f : 0.0f;
            if (s >= 16) {
                float m0 = y0 * unocc, m1 = y1 * occ;
                float nrm = fmaxf(sqrtf(m0 * m0 + m1 * m1), 1e-12f);
                float rn  = rcp_fast(nrm);
                y0 = m0 * rn; y1 = m1 * rn;
            }
            if (is_even) nu += (float)bit; else nd += (float)bit;
            amp *= bit ? y1 : y0;
            phs += bit ? ph1 : ph0;
        }
    }

    if (wv < 4 && q == 0) {
        int eg = ebg + eh;
        if (eg < nbatch) {
            float s, c;
            sincosf(phs, &s, &c);
            out[eg]          = amp * c;
            out[nbatch + eg] = amp * s;
        }
    }
}

extern "C" void kernel_launch(void* const* d_in, const int* in_sizes, int n_in,
                              void* d_out, int out_size, void* d_ws, size_t ws_size,
                              hipStream_t stream) {
    const int*   x     = (const int*)  d_in[0];
    const float* w_ih0 = (const float*)d_in[1];
    const float* w_hh0 = (const float*)d_in[2];
    const float* w_ih1 = (const float*)d_in[3];
    const float* w_hh1 = (const float*)d_in[4];
    const float* w_lin = (const float*)d_in[5];
    const float* b_lin = (const float*)d_in[6];
    float* out = (float*)d_out;
    _Float16* wsp = (_Float16*)d_ws;

    const int nbatch = in_sizes[0] / 64;

    prep_kernel<<<384, 256, 0, stream>>>(w_hh0, w_ih1, w_hh1, wsp);

    const int blocks = (nbatch + 63) / 64;
    rnn_wf_pipe<<<blocks, 512, 0, stream>>>(x, w_ih0, w_lin, b_lin, wsp, out, nbatch);
}

// Round 14
// 1553.197 us; speedup vs baseline: 1.0382x; 1.0219x over previous
//
#include <hip/hip_runtime.h>
#include <math.h>

#define PI_F 3.14159265358979323846f

typedef _Float16 half8 __attribute__((ext_vector_type(8)));
typedef _Float16 half4 __attribute__((ext_vector_type(4)));
typedef float f32x4 __attribute__((ext_vector_type(4)));

#define MFMA(a, b, c) __builtin_amdgcn_mfma_f32_16x16x32_f16(a, b, c, 0, 0, 0)
#define OFF_CAT 49152   // halfs: wcat starts after whh0 (3*128*128)

__device__ __forceinline__ float rcp_fast(float x) { return __builtin_amdgcn_rcpf(x); }
__device__ __forceinline__ float sigmoid_f(float x) {
    float e = __expf(-x);
    return rcp_fast(1.0f + e);
}
__device__ __forceinline__ float tanh_f(float x) {
    float ax = fabsf(x);
    float e  = __expf(-2.0f * ax);
    float t  = (1.0f - e) * rcp_fast(1.0f + e);
    return x >= 0.0f ? t : -t;
}

// Prep: f16 weights; concat [w_ih1|w_hh1] along K for layer 1.
__global__ void prep_kernel(const float* __restrict__ whh0,
                            const float* __restrict__ wih1,
                            const float* __restrict__ whh1,
                            _Float16* __restrict__ wsp) {
    int i = blockIdx.x * 256 + threadIdx.x;
    if (i < 49152) wsp[i] = (_Float16)whh0[i];
    if (i < 98304) {
        int n = i >> 8, k = i & 255;
        float v = (k < 128) ? wih1[(n << 7) + k] : whh1[(n << 7) + k - 128];
        wsp[OFF_CAT + i] = (_Float16)v;
    }
}

// 512 threads (8 waves), 64 elems/block, 1 block/CU, 2 waves/SIMD, 256 regs.
// r11 base (1539us, best): 16 dims/wave both layers, weights resident (144
// regs, "+v"-pinned), own-dim h state in f32 registers, f16 h planes in LDS,
// 2 barriers/tick { A | bar | B | bar | head || A(t+1) }.
// Falsified levers (do not revisit): barrier fusion (r3/r7/r9), layer-split
// waves (r6), AGPR pins (r10), half-tick interleave (r12), x-barrier
// prefetch (r13).
//
// Round-14 change: DISTRIBUTED HEAD PARTIALS. The head was serial critical-
// path: waves 4-7 idle at bar1(t+1) while waves 0-3 run it (~250-300 cyc:
// 4 b128 f16 reads + 32 cvt + 64 fma + 4 shfl). But after B's epilogue the
// block holds h1(t) ENTIRELY in f32 registers (lane (q,l4) of wave wv: dims
// d0..d0+3 of elems eb*16+l4). So each lane folds its slice into the two
// logits (8 fma, in-reg), q-reduces via shfl_xor(16/32), and q==0 lanes
// write 2 floats/elem/wave to padded scratch (rows 48B: bank stride 12 ->
// 2-way = free). After the EXISTING bar2 the head-finish is 4 b128 scratch
// reads + 14 adds + scalar epilogue (~80 cyc tail). The partial work is
// absorbed by all 8 waves inside the fat B window. Logits now use exact f32
// h1 (reference-closer than the old f16-rounded LDS path).
// Scratch hazards: written pre-bar2(t), read post-bar2(t); next write is in
// B(t+1) after bar1(t+1), reached by waves 0-3 only after head(t) -> safe.
//
// h planes (64 elems) in MFMA-B-frag chunk order, double-buffered by parity:
//   plane[buf][(kc*4 + eb)*512 + (qd*16 + l4)*8 + j] = h[e=eb*16+l4][dim=32kc+8qd+j]

__global__ void __launch_bounds__(512, 2) rnn_wf_pipe(
    const int*   __restrict__ x,
    const float* __restrict__ w_ih0,
    const float* __restrict__ w_lin,
    const float* __restrict__ b_lin,
    const _Float16* __restrict__ wsp,
    float*       __restrict__ out,
    int nbatch)
{
    __shared__ _Float16 h0[2][8192], h1[2][8192];
    __shared__ float gi0T[2][3][128];          // [prev-bit][gate][dim]
    __shared__ float hsc0[64][12], hsc1[64][12];  // head partials [elem][wave(+pad)]
    __shared__ unsigned long long bmk[64];     // per-element bit mask

    const int t    = threadIdx.x;
    const int wv   = t >> 6;                   // 0..7 = dim-block (16 dims)
    const int l4   = t & 15;
    const int q    = (t >> 4) & 3;
    const int ebg  = blockIdx.x * 64;

    // ---- init LDS ----
    for (int i = t; i < 8192; i += 512) {      // 8192 ints = 2 bufs x 8192 halfs per array
        ((int*)h0)[i] = 0; ((int*)h1)[i] = 0;
    }
    for (int i = t; i < 768; i += 512) {
        int b = i / 384, rem = i - b * 384;
        ((float*)gi0T)[b * 384 + rem] = w_ih0[rem * 2 + b];
    }
    if (t < 256) {   // bit masks: thread t -> element t>>2, quarter t&3
        int el = t >> 2, qq = t & 3;
        int eg = ebg + el; if (eg >= nbatch) eg = nbatch - 1;
        const int* xr = x + (size_t)eg * 64 + qq * 16;
        unsigned long long m = 0ull;
#pragma unroll
        for (int i = 0; i < 16; ++i)
            m |= ((unsigned long long)((unsigned)(xr[i] + 1) >> 1)) << (qq * 16 + i);
        m |= __shfl_xor(m, 1);
        m |= __shfl_xor(m, 2);
        if (qq == 0) bmk[el] = m;
    }

    const int lo8 = ((q << 4) + l4) << 3;      // = lane*8 halfs: B-frag chunk offset
    const int d0  = wv * 16 + 4 * q;           // first of 4 dims this lane updates
    const int epb = (d0 >> 5) * 2048 + ((d0 >> 3) & 3) * 128 + l4 * 8 + (d0 & 7);

    // ---- register-resident weights ----
    half8 w0[3][4];                            // 48 regs
#pragma unroll
    for (int g = 0; g < 3; ++g)
#pragma unroll
        for (int kc = 0; kc < 4; ++kc)
            w0[g][kc] = *(const half8*)(wsp + (size_t)(g * 128 + 16 * wv + l4) * 128 + 32 * kc + 8 * q);
    half8 w1[3][8];                            // 96 regs
#pragma unroll
    for (int g = 0; g < 3; ++g)
#pragma unroll
        for (int kc = 0; kc < 8; ++kc)
            w1[g][kc] = *(const half8*)(wsp + OFF_CAT + (size_t)(g * 128 + 16 * wv + l4) * 256 + 32 * kc + 8 * q);

    // ---- per-lane w_lin slice for head partials (dims d0..d0+3) ----
    f32x4 wlA, wlB;
#pragma unroll
    for (int r = 0; r < 4; ++r) {
        wlA[r] = w_lin[d0 + r];
        wlB[r] = w_lin[128 + d0 + r];
    }

    // ---- own-dim h state in f32 registers (statically indexed) ----
    f32x4 h0s[4], h1s[4];
#pragma unroll
    for (int eb = 0; eb < 4; ++eb) {
        h0s[eb] = (f32x4){0.f, 0.f, 0.f, 0.f};
        h1s[eb] = (f32x4){0.f, 0.f, 0.f, 0.f};
    }

    // head state (waves 0-3, q-replicated)
    float amp = 1.0f, phs = 0.0f, nu = 0.0f, nd = 0.0f;
    float bl0 = 0.0f, bl1 = 0.0f;
    const int eh = (wv << 4) + l4;
    if (wv < 4) { bl0 = b_lin[0]; bl1 = b_lin[1]; }

    __syncthreads();

    for (int tick = 0; tick < 64; ++tick) {
        const int cur = tick & 1, prv = cur ^ 1;

        // pin weights: opaque loop-carried registers (no remat from memory)
#pragma unroll
        for (int g = 0; g < 3; ++g) {
#pragma unroll
            for (int kc = 0; kc < 4; ++kc) asm volatile("" : "+v"(w0[g][kc]));
#pragma unroll
            for (int kc = 0; kc < 8; ++kc) asm volatile("" : "+v"(w1[g][kc]));
        }

        // ---- Phase A: h0(tick) = GRU0(onehot(bit(tick-1)), h0(tick-1)) ----
#pragma unroll
        for (int eb = 0; eb < 4; ++eb) {
            f32x4 aR = {0,0,0,0}, aZ = {0,0,0,0}, aN = {0,0,0,0};
#pragma unroll
            for (int kc = 0; kc < 4; ++kc) {
                const int cb = (kc * 4 + eb) * 512 + lo8;
                half8 hh = *(const half8*)&h0[prv][cb];
                aR = MFMA(w0[0][kc], hh, aR);
                aZ = MFMA(w0[1][kc], hh, aZ);
                aN = MFMA(w0[2][kc], hh, aN);
            }
            const int e = eb * 16 + l4;
            f32x4 giR = {0,0,0,0}, giZ = {0,0,0,0}, giN = {0,0,0,0};
            if (tick > 0) {
                int pb = (int)((bmk[e] >> (tick - 1)) & 1ull);
                const float* gp = &gi0T[pb][0][0];
                giR = *(const f32x4*)(gp + d0);
                giZ = *(const f32x4*)(gp + 128 + d0);
                giN = *(const f32x4*)(gp + 256 + d0);
            }
            const int ep_ = epb + eb * 512;
            f32x4 hp = h0s[eb];
            f32x4 hnv;
            half4 nh;
#pragma unroll
            for (int r = 0; r < 4; ++r) {
                float rr = sigmoid_f(giR[r] + aR[r]);
                float zz = sigmoid_f(giZ[r] + aZ[r]);
                float nn = tanh_f(giN[r] + rr * aN[r]);
                float hn = (1.0f - zz) * nn + zz * hp[r];
                hnv[r] = hn;
                nh[r] = (_Float16)hn;
            }
            h0s[eb] = hnv;
            *(half4*)&h0[cur][ep_] = nh;
        }

        __syncthreads();

        // ---- Phase B: h1(tick) = GRU1(h0(tick), h1(tick-1)) ----
        //      + distributed head partials from exact f32 h1 (in-reg)
#pragma unroll
        for (int eb = 0; eb < 4; ++eb) {
            f32x4 aR = {0,0,0,0}, aZ = {0,0,0,0};
            f32x4 aNi = {0,0,0,0}, aNh = {0,0,0,0};
#pragma unroll
            for (int kc = 0; kc < 8; ++kc) {
                const int cb = ((kc & 3) * 4 + eb) * 512 + lo8;
                half8 hh;
                if (kc < 4) hh = *(const half8*)&h0[cur][cb];
                else        hh = *(const half8*)&h1[prv][cb];
                aR = MFMA(w1[0][kc], hh, aR);
                aZ = MFMA(w1[1][kc], hh, aZ);
                if (kc < 4) aNi = MFMA(w1[2][kc], hh, aNi);
                else        aNh = MFMA(w1[2][kc], hh, aNh);
            }
            const int ep_ = epb + eb * 512;
            f32x4 hp = h1s[eb];
            f32x4 hnv;
            half4 nh;
#pragma unroll
            for (int r = 0; r < 4; ++r) {
                float rr = sigmoid_f(aR[r]);
                float zz = sigmoid_f(aZ[r]);
                float nn = tanh_f(aNi[r] + rr * aNh[r]);
                float hn = (1.0f - zz) * nn + zz * hp[r];
                hnv[r] = hn;
                nh[r] = (_Float16)hn;
            }
            h1s[eb] = hnv;
            *(half4*)&h1[cur][ep_] = nh;

            // head partial for elem eb*16+l4: this lane's 4-dim slice
            float pl0 = hnv[0] * wlA[0];
            float pl1 = hnv[0] * wlB[0];
#pragma unroll
            for (int r = 1; r < 4; ++r) {
                pl0 = fmaf(hnv[r], wlA[r], pl0);
                pl1 = fmaf(hnv[r], wlB[r], pl1);
            }
            pl0 += __shfl_xor(pl0, 16); pl0 += __shfl_xor(pl0, 32);
            pl1 += __shfl_xor(pl1, 16); pl1 += __shfl_xor(pl1, 32);
            if (q == 0) {
                hsc0[eb * 16 + l4][wv] = pl0;
                hsc1[eb * 16 + l4][wv] = pl1;
            }
        }

        __syncthreads();

        // ---- head-finish for step s = tick.  Waves 0-3 only; waves 4-7
        //      proceed straight into A(tick+1) (disjoint arrays).
        //      4 b128 scratch reads + 14 adds -- short tail. ----
        if (wv < 4) {
            const int s = tick;
            f32x4 p0a = *(const f32x4*)&hsc0[eh][0];
            f32x4 p0b = *(const f32x4*)&hsc0[eh][4];
            f32x4 p1a = *(const f32x4*)&hsc1[eh][0];
            f32x4 p1b = *(const f32x4*)&hsc1[eh][4];
            float l0 = bl0 + ((p0a[0] + p0a[1]) + (p0a[2] + p0a[3]))
                           + ((p0b[0] + p0b[1]) + (p0b[2] + p0b[3]));
            float l1 = bl1 + ((p1a[0] + p1a[1]) + (p1a[2] + p1a[3]))
                           + ((p1b[0] + p1b[1]) + (p1b[2] + p1b[3]));

            float p0 = sigmoid_f(l0 - l1);
            float p1 = sigmoid_f(l1 - l0);
            float y0 = sqrtf(p0), y1 = sqrtf(p1);
            float ph0 = PI_F * l0 * rcp_fast(1.0f + fabsf(l0));
            float ph1 = PI_F * l1 * rcp_fast(1.0f + fabsf(l1));

            int bit = (int)((bmk[eh] >> s) & 1ull);
            bool is_even = (s & 1) == 0;
            float num   = is_even ? nu : nd;
            float lower = -16.0f + (float)(s >> 1);
            float occ   = (num < 16.0f) ? 1.0f : 0.0f;
            float unocc = (num > lower) ? 1.0f : 0.0f;
            if (s >= 16) {
                float m0 = y0 * unocc, m1 = y1 * occ;
                float nrm = fmaxf(sqrtf(m0 * m0 + m1 * m1), 1e-12f);
                float rn  = rcp_fast(nrm);
                y0 = m0 * rn; y1 = m1 * rn;
            }
            if (is_even) nu += (float)bit; else nd += (float)bit;
            amp *= bit ? y1 : y0;
            phs += bit ? ph1 : ph0;
        }
    }

    if (wv < 4 && q == 0) {
        int eg = ebg + eh;
        if (eg < nbatch) {
            float s, c;
            sincosf(phs, &s, &c);
            out[eg]          = amp * c;
            out[nbatch + eg] = amp * s;
        }
    }
}

extern "C" void kernel_launch(void* const* d_in, const int* in_sizes, int n_in,
                              void* d_out, int out_size, void* d_ws, size_t ws_size,
                              hipStream_t stream) {
    const int*   x     = (const int*)  d_in[0];
    const float* w_ih0 = (const float*)d_in[1];
    const float* w_hh0 = (const float*)d_in[2];
    const float* w_ih1 = (const float*)d_in[3];
    const float* w_hh1 = (const float*)d_in[4];
    const float* w_lin = (const float*)d_in[5];
    const float* b_lin = (const float*)d_in[6];
    float* out = (float*)d_out;
    _Float16* wsp = (_Float16*)d_ws;

    const int nbatch = in_sizes[0] / 64;

    prep_kernel<<<384, 256, 0, stream>>>(w_hh0, w_ih1, w_hh1, wsp);

    const int blocks = (nbatch + 63) / 64;
    rnn_wf_pipe<<<blocks, 512, 0, stream>>>(x, w_ih0, w_lin, b_lin, wsp, out, nbatch);
}

// Round 15
// 1524.208 us; speedup vs baseline: 1.0580x; 1.0190x over previous
//
#include <hip/hip_runtime.h>
#include <math.h>

#define PI_F 3.14159265358979323846f

typedef _Float16 half8 __attribute__((ext_vector_type(8)));
typedef _Float16 half4 __attribute__((ext_vector_type(4)));
typedef float f32x4 __attribute__((ext_vector_type(4)));

#define MFMA(a, b, c) __builtin_amdgcn_mfma_f32_16x16x32_f16(a, b, c, 0, 0, 0)
#define OFF_CAT 49152   // halfs: wcat starts after whh0 (3*128*128)

__device__ __forceinline__ float rcp_fast(float x) { return __builtin_amdgcn_rcpf(x); }
__device__ __forceinline__ float sigmoid_f(float x) {
    float e = __expf(-x);
    return rcp_fast(1.0f + e);
}
__device__ __forceinline__ float tanh_f(float x) {
    float ax = fabsf(x);
    float e  = __expf(-2.0f * ax);
    float t  = (1.0f - e) * rcp_fast(1.0f + e);
    return x >= 0.0f ? t : -t;
}

// Prep: f16 weights; concat [w_ih1|w_hh1] along K for layer 1.
__global__ void prep_kernel(const float* __restrict__ whh0,
                            const float* __restrict__ wih1,
                            const float* __restrict__ whh1,
                            _Float16* __restrict__ wsp) {
    int i = blockIdx.x * 256 + threadIdx.x;
    if (i < 49152) wsp[i] = (_Float16)whh0[i];
    if (i < 98304) {
        int n = i >> 8, k = i & 255;
        float v = (k < 128) ? wih1[(n << 7) + k] : whh1[(n << 7) + k - 128];
        wsp[OFF_CAT + i] = (_Float16)v;
    }
}

// 512 threads (8 waves), now 128 elems/block, 1 block/CU (LDS 133KB), 2
// waves/SIMD, 256 regs. r11 inner structure (best, 1539us): 16 dims/wave
// both layers, weights resident (144 regs, "+v"-pinned), own-dim h state in
// f32 registers, f16 h planes in LDS, 2 barriers/tick
//     { A: h0(t) | bar | B: h1(t) | bar | head(t) }.
// Falsified levers (do not revisit): barrier fusion (r3/r7/r9), layer-split
// waves (r6), AGPR pins (r10), half-tick interleave (r12), x-barrier
// prefetch (r13), distributed head (r14).
//
// Round-15 change: FIXED-COST AMORTIZATION. Wall = 13.2K cyc/block-tick =
// MFMA 5.3K + VALU ~4.8K + ~3K per-tick FIXED cost (2 lockstep barrier
// drains, loop control, pin-constrained regalloc, phase ramp). 64-elem
// blocks ran 4 sequential rounds/CU -> 256 tick-payments of F. 128-elem
// blocks run 2 clean rounds (512 blocks / 256 CUs): wall/CU drops from
// 256(F+V) to 128(F+2V) -- saves 128F. eb loop 4 -> 8; head now on all 8
// waves (each owns its 16 elems). Per-element arithmetic IDENTICAL to r11
// -> absmax must reproduce 1.164153e-10 bit-exactly.
// Register risk: state regs double to 64; ~250-260 live vs 256 cap --
// WRITE_SIZE diagnoses spill (falsifier -> revert).
//
// h planes (128 elems) in MFMA-B-frag chunk order, double-buffered:
//   plane[buf][(kc*8 + eb)*512 + (qd*16 + l4)*8 + j] = h[e=eb*16+l4][dim=32kc+8qd+j]

__global__ void __launch_bounds__(512, 2) rnn_wf_pipe(
    const int*   __restrict__ x,
    const float* __restrict__ w_ih0,
    const float* __restrict__ w_lin,
    const float* __restrict__ b_lin,
    const _Float16* __restrict__ wsp,
    float*       __restrict__ out,
    int nbatch)
{
    __shared__ _Float16 h0[2][16384], h1[2][16384];
    __shared__ float gi0T[2][3][128];          // [prev-bit][gate][dim]
    __shared__ float wlinT[256];               // w_lin flat
    __shared__ unsigned long long bmk[128];    // per-element bit mask

    const int t    = threadIdx.x;
    const int wv   = t >> 6;                   // 0..7 = dim-block (16 dims)
    const int l4   = t & 15;
    const int q    = (t >> 4) & 3;
    const int ebg  = blockIdx.x * 128;

    // ---- init LDS ----
    for (int i = t; i < 16384; i += 512) {     // 16384 ints = 2 bufs x 16384 halfs per array
        ((int*)h0)[i] = 0; ((int*)h1)[i] = 0;
    }
    for (int i = t; i < 768; i += 512) {
        int b = i / 384, rem = i - b * 384;
        ((float*)gi0T)[b * 384 + rem] = w_ih0[rem * 2 + b];
    }
    if (t < 256) wlinT[t] = w_lin[t];
    {   // bit masks: thread t -> element t>>2 (0..127), quarter t&3
        int el = t >> 2, qq = t & 3;
        int eg = ebg + el; if (eg >= nbatch) eg = nbatch - 1;
        const int* xr = x + (size_t)eg * 64 + qq * 16;
        unsigned long long m = 0ull;
#pragma unroll
        for (int i = 0; i < 16; ++i)
            m |= ((unsigned long long)((unsigned)(xr[i] + 1) >> 1)) << (qq * 16 + i);
        m |= __shfl_xor(m, 1);
        m |= __shfl_xor(m, 2);
        if (qq == 0) bmk[el] = m;
    }

    const int lo8 = ((q << 4) + l4) << 3;      // = lane*8 halfs: B-frag chunk offset
    const int d0  = wv * 16 + 4 * q;           // first of 4 dims this lane updates
    const int epb = (d0 >> 5) * 4096 + ((d0 >> 3) & 3) * 128 + l4 * 8 + (d0 & 7);

    // ---- register-resident weights ----
    half8 w0[3][4];                            // 48 regs
#pragma unroll
    for (int g = 0; g < 3; ++g)
#pragma unroll
        for (int kc = 0; kc < 4; ++kc)
            w0[g][kc] = *(const half8*)(wsp + (size_t)(g * 128 + 16 * wv + l4) * 128 + 32 * kc + 8 * q);
    half8 w1[3][8];                            // 96 regs
#pragma unroll
    for (int g = 0; g < 3; ++g)
#pragma unroll
        for (int kc = 0; kc < 8; ++kc)
            w1[g][kc] = *(const half8*)(wsp + OFF_CAT + (size_t)(g * 128 + 16 * wv + l4) * 256 + 32 * kc + 8 * q);

    // ---- own-dim h state in f32 registers (statically indexed) ----
    f32x4 h0s[8], h1s[8];
#pragma unroll
    for (int eb = 0; eb < 8; ++eb) {
        h0s[eb] = (f32x4){0.f, 0.f, 0.f, 0.f};
        h1s[eb] = (f32x4){0.f, 0.f, 0.f, 0.f};
    }

    // head state (all 8 waves, q-replicated): wave wv owns elems wv*16..+15
    float amp = 1.0f, phs = 0.0f, nu = 0.0f, nd = 0.0f;
    const float bl0 = b_lin[0], bl1 = b_lin[1];
    const int eh = (wv << 4) + l4;

    __syncthreads();

    for (int tick = 0; tick < 64; ++tick) {
        const int cur = tick & 1, prv = cur ^ 1;

        // pin weights: opaque loop-carried registers (no remat from memory)
#pragma unroll
        for (int g = 0; g < 3; ++g) {
#pragma unroll
            for (int kc = 0; kc < 4; ++kc) asm volatile("" : "+v"(w0[g][kc]));
#pragma unroll
            for (int kc = 0; kc < 8; ++kc) asm volatile("" : "+v"(w1[g][kc]));
        }

        // ---- Phase A: h0(tick) = GRU0(onehot(bit(tick-1)), h0(tick-1)) ----
#pragma unroll
        for (int eb = 0; eb < 8; ++eb) {
            f32x4 aR = {0,0,0,0}, aZ = {0,0,0,0}, aN = {0,0,0,0};
#pragma unroll
            for (int kc = 0; kc < 4; ++kc) {
                const int cb = (kc * 8 + eb) * 512 + lo8;
                half8 hh = *(const half8*)&h0[prv][cb];
                aR = MFMA(w0[0][kc], hh, aR);
                aZ = MFMA(w0[1][kc], hh, aZ);
                aN = MFMA(w0[2][kc], hh, aN);
            }
            const int e = eb * 16 + l4;
            f32x4 giR = {0,0,0,0}, giZ = {0,0,0,0}, giN = {0,0,0,0};
            if (tick > 0) {
                int pb = (int)((bmk[e] >> (tick - 1)) & 1ull);
                const float* gp = &gi0T[pb][0][0];
                giR = *(const f32x4*)(gp + d0);
                giZ = *(const f32x4*)(gp + 128 + d0);
                giN = *(const f32x4*)(gp + 256 + d0);
            }
            const int ep_ = epb + eb * 512;
            f32x4 hp = h0s[eb];
            f32x4 hnv;
            half4 nh;
#pragma unroll
            for (int r = 0; r < 4; ++r) {
                float rr = sigmoid_f(giR[r] + aR[r]);
                float zz = sigmoid_f(giZ[r] + aZ[r]);
                float nn = tanh_f(giN[r] + rr * aN[r]);
                float hn = (1.0f - zz) * nn + zz * hp[r];
                hnv[r] = hn;
                nh[r] = (_Float16)hn;
            }
            h0s[eb] = hnv;
            *(half4*)&h0[cur][ep_] = nh;
        }

        __syncthreads();

        // ---- Phase B: h1(tick) = GRU1(h0(tick), h1(tick-1)) ----
#pragma unroll
        for (int eb = 0; eb < 8; ++eb) {
            f32x4 aR = {0,0,0,0}, aZ = {0,0,0,0};
            f32x4 aNi = {0,0,0,0}, aNh = {0,0,0,0};
#pragma unroll
            for (int kc = 0; kc < 8; ++kc) {
                const int cb = ((kc & 3) * 8 + eb) * 512 + lo8;
                half8 hh;
                if (kc < 4) hh = *(const half8*)&h0[cur][cb];
                else        hh = *(const half8*)&h1[prv][cb];
                aR = MFMA(w1[0][kc], hh, aR);
                aZ = MFMA(w1[1][kc], hh, aZ);
                if (kc < 4) aNi = MFMA(w1[2][kc], hh, aNi);
                else        aNh = MFMA(w1[2][kc], hh, aNh);
            }
            const int ep_ = epb + eb * 512;
            f32x4 hp = h1s[eb];
            f32x4 hnv;
            half4 nh;
#pragma unroll
            for (int r = 0; r < 4; ++r) {
                float rr = sigmoid_f(aR[r]);
                float zz = sigmoid_f(aZ[r]);
                float nn = tanh_f(aNi[r] + rr * aNh[r]);
                float hn = (1.0f - zz) * nn + zz * hp[r];
                hnv[r] = hn;
                nh[r] = (_Float16)hn;
            }
            h1s[eb] = hnv;
            *(half4*)&h1[cur][ep_] = nh;
        }

        __syncthreads();

        // ---- head for step s = tick; h1(s) in buf cur.  ALL 8 waves, each
        //      owning its 16 elems. Lane-linear reads (conflict-free);
        //      xor-16/32 reduce combines q-groups. ----
        {
            const int s = tick;
            float l0 = 0.0f, l1 = 0.0f;
#pragma unroll
            for (int ks = 0; ks < 4; ++ks) {
                const int cb = (ks * 8 + wv) * 512 + lo8;
                half8 hh = *(const half8*)&h1[cur][cb];
                const float* wpl = &wlinT[32 * ks + 8 * q];
#pragma unroll
                for (int j = 0; j < 8; ++j) {
                    float hv = (float)hh[j];
                    l0 = fmaf(hv, wpl[j], l0);
                    l1 = fmaf(hv, wpl[128 + j], l1);
                }
            }
            l0 += __shfl_xor(l0, 16); l0 += __shfl_xor(l0, 32); l0 += bl0;
            l1 += __shfl_xor(l1, 16); l1 += __shfl_xor(l1, 32); l1 += bl1;

            float p0 = sigmoid_f(l0 - l1);
            float p1 = sigmoid_f(l1 - l0);
            float y0 = sqrtf(p0), y1 = sqrtf(p1);
            float ph0 = PI_F * l0 * rcp_fast(1.0f + fabsf(l0));
            float ph1 = PI_F * l1 * rcp_fast(1.0f + fabsf(l1));

            int bit = (int)((bmk[eh] >> s) & 1ull);
            bool is_even = (s & 1) == 0;
            float num   = is_even ? nu : nd;
            float lower = -16.0f + (float)(s >> 1);
            float occ   = (num < 16.0f) ? 1.0f : 0.0f;
            float unocc = (num > lower) ? 1.0f : 0.0f;
            if (s >= 16) {
                float m0 = y0 * unocc, m1 = y1 * occ;
                float nrm = fmaxf(sqrtf(m0 * m0 + m1 * m1), 1e-12f);
                float rn  = rcp_fast(nrm);
                y0 = m0 * rn; y1 = m1 * rn;
            }
            if (is_even) nu += (float)bit; else nd += (float)bit;
            amp *= bit ? y1 : y0;
            phs += bit ? ph1 : ph0;
        }
    }

    if (q == 0) {
        int eg = ebg + eh;
        if (eg < nbatch) {
            float s, c;
            sincosf(phs, &s, &c);
            out[eg]          = amp * c;
            out[nbatch + eg] = amp * s;
        }
    }
}

extern "C" void kernel_launch(void* const* d_in, const int* in_sizes, int n_in,
                              void* d_out, int out_size, void* d_ws, size_t ws_size,
                              hipStream_t stream) {
    const int*   x     = (const int*)  d_in[0];
    const float* w_ih0 = (const float*)d_in[1];
    const float* w_hh0 = (const float*)d_in[2];
    const float* w_ih1 = (const float*)d_in[3];
    const float* w_hh1 = (const float*)d_in[4];
    const float* w_lin = (const float*)d_in[5];
    const float* b_lin = (const float*)d_in[6];
    float* out = (float*)d_out;
    _Float16* wsp = (_Float16*)d_ws;

    const int nbatch = in_sizes[0] / 64;

    prep_kernel<<<384, 256, 0, stream>>>(w_hh0, w_ih1, w_hh1, wsp);

    const int blocks = (nbatch + 127) / 128;
    rnn_wf_pipe<<<blocks, 512, 0, stream>>>(x, w_ih0, w_lin, b_lin, wsp, out, nbatch);
}